// Round 12
// baseline (1111.998 us; speedup 1.0000x reference)
//
#include <hip/hip_runtime.h>
#include <stdint.h>

#define R_NODES 256
#define M_SAMP  512
#define S_STEPS 512
#define OUT_N   10

typedef unsigned int u32x2 __attribute__((ext_vector_type(2)));

// ---------------- layout detection for bool inputs ----------------
// If bools were uploaded as int32, byte (4f+1) of every element is 0.
// If uploaded as uint8, ~half those bytes are 1.  flag=1 => uint8 layout.
__global__ void detect_layout(const uint8_t* __restrict__ x, int* __restrict__ flag) {
    __shared__ int any;
    if (threadIdx.x == 0) any = 0;
    __syncthreads();
    int acc = 0;
    for (int i = 0; i < 64; ++i)
        acc |= x[(size_t)(threadIdx.x * 64 + i) * 4 + 1];
    if (acc) atomicOr(&any, 1);
    __syncthreads();
    if (threadIdx.x == 0) *flag = any ? 1 : 0;
}

// ---------------- pack x bits: one uint32 per (m,s) ----------------
__global__ void pack_x(const uint8_t* __restrict__ x, const int* __restrict__ flag,
                       uint32_t* __restrict__ xp) {
    const int stride = (*flag) ? 1 : 4;
    const int f = blockIdx.x * blockDim.x + threadIdx.x;      // element idx, M*S*32 total
    const int val = x[(size_t)f * stride];
    const uint64_t mask = __ballot(val != 0);
    const int lane = threadIdx.x & 63;
    if ((lane & 31) == 0) {
        uint32_t w = (lane & 32) ? (uint32_t)(mask >> 32) : (uint32_t)mask;
        xp[f >> 5] = w;
    }
}

// ---------------- bit-pack the LUT: 256MB int32 -> 8MB bits ----------------
__device__ __forceinline__ uint32_t spread8(uint32_t x) {
    // bit i of low byte -> bit 4*i
    x = (x | (x << 12)) & 0x000F000Fu;
    x = (x | (x << 6))  & 0x03030303u;
    x = (x | (x << 3))  & 0x11111111u;
    return x;
}
__global__ void pack_lut(const int* __restrict__ lut, uint32_t* __restrict__ lp32) {
    const int lane = threadIdx.x & 63;
    const int gw = blockIdx.x * (blockDim.x >> 6) + (threadIdx.x >> 6); // 16384 waves
    const int4* src = (const int4*)lut;
    for (int it = 0; it < 16; ++it) {
        const int chunk = gw * 16 + it;                // 262144 wave-chunks total
        const int4 q = src[(size_t)chunk * 64 + lane]; // coalesced 16B/lane
        const uint64_t b0 = __ballot((q.x & 1) != 0);
        const uint64_t b1 = __ballot((q.y & 1) != 0);
        const uint64_t b2 = __ballot((q.z & 1) != 0);
        const uint64_t b3 = __ballot((q.w & 1) != 0);
        if (lane < 8) {
            const uint32_t B0 = (uint32_t)(b0 >> (8 * lane)) & 0xFF;
            const uint32_t B1 = (uint32_t)(b1 >> (8 * lane)) & 0xFF;
            const uint32_t B2 = (uint32_t)(b2 >> (8 * lane)) & 0xFF;
            const uint32_t B3 = (uint32_t)(b3 >> (8 * lane)) & 0xFF;
            const uint32_t w = spread8(B0) | (spread8(B1) << 1)
                             | (spread8(B2) << 2) | (spread8(B3) << 3);
            lp32[(size_t)chunk * 8 + lane] = w;
        }
    }
}

// ------------- main scan: bitplane popcount, TWO samples per thread -------
// R11 (701us, 3285cy/step): single-sample popcount left the lp load and
// barrier naked at the chain's end with only 2 phase-locked blocks/CU.
// This version: block = 256 threads handles samples 2m and 2m+1; thread j
// keeps ONE copy of the PW[11][8] bit-plane tables (88 VGPRs, sample-
// independent) and two 8-word state masks.  Per step, software-pipelined
// in-thread:
//   idxA (88 and + 88 bcnt) -> issue lpA -> idxB (hides lpA latency) ->
//   issue lpB -> vmcnt(1) extract A -> vmcnt(0) extract B -> ballots ->
//   ONE barrier.  In-loop VMEM = exactly the two asm loads -> counted
//   vmcnt is exact.  ~1400cy per 2-sample step (~700/sample vs 3285).
// Grid 256 blocks = 1 block/CU exactly; all CUs busy.
__global__ __launch_bounds__(256, 1) void reservoir_pop2(
    const uint32_t* __restrict__ xp, const uint64_t* __restrict__ lp,
    const int* __restrict__ input_nodes, const uint8_t* __restrict__ wres,
    const int* __restrict__ primes, const uint8_t* __restrict__ init_res,
    const int* __restrict__ flag, const float* __restrict__ rW,
    const float* __restrict__ rb, float* __restrict__ out)
{
    const int m2 = blockIdx.x;          // samples 2*m2 (A), 2*m2+1 (B)
    const int j = threadIdx.x;          // node 0..255
    const int l = j & 63;
    const int w = j >> 6;               // wave 0..3
    const int stride = (*flag) ? 1 : 4;

    __shared__ uint32_t sxwA[S_STEPS], sxwB[S_STEPS];
    __shared__ uint32_t rmask[2][2][8]; // [dbuf][sample][word]
    __shared__ float    lout[2][OUT_N];

    const uint32_t* xrowA = xp + (2 * m2 + 0) * S_STEPS;
    const uint32_t* xrowB = xp + (2 * m2 + 1) * S_STEPS;
    for (int i = j; i < S_STEPS; i += 256) { sxwA[i] = xrowA[i]; sxwB[i] = xrowB[i]; }

    int slot = -1;
    for (int i = 0; i < 32; ++i)
        if (input_nodes[i] == j) slot = i;

    // ---- build bit-planes once (static indices -> 88 VGPRs) ----
    uint32_t PW[11][8];
#pragma unroll
    for (int b = 0; b < 11; ++b)
#pragma unroll
        for (int q = 0; q < 8; ++q) PW[b][q] = 0;
#pragma unroll
    for (int q = 0; q < 8; ++q) {
        for (int bit = 0; bit < 32; ++bit) {
            const int k = 32 * q + bit;
            const uint32_t on = wres[(size_t)(j * 256 + k) * stride] ? 1u : 0u;
            const uint32_t p  = on * (uint32_t)primes[k];
#pragma unroll
            for (int b = 0; b < 11; ++b)
                PW[b][q] |= ((p >> b) & 1u) << bit;
        }
    }

    __syncthreads();                    // sxw ready
    {
        const int iv = init_res[(size_t)j * stride] ? 1 : 0;
        int bvA = iv, bvB = iv;
        if (slot >= 0) { bvA = (sxwA[0] >> slot) & 1; bvB = (sxwB[0] >> slot) & 1; }
        const uint64_t balA = __ballot(bvA != 0);
        const uint64_t balB = __ballot(bvB != 0);
        if (l == 0) {
            rmask[0][0][2 * w] = (uint32_t)balA;  rmask[0][0][2 * w + 1] = (uint32_t)(balA >> 32);
            rmask[0][1][2 * w] = (uint32_t)balB;  rmask[0][1][2 * w + 1] = (uint32_t)(balB >> 32);
        }
    }
    __syncthreads();

    const uint64_t lpbase = (uint64_t)(uintptr_t)lp;
    int cur = 0, vA = 0, vB = 0;

#define IDX_OF(R, OUTV) do {                                                  \
        uint32_t acc_ = 0;                                                    \
        _Pragma("unroll")                                                     \
        for (int b_ = 0; b_ < 11; ++b_) {                                     \
            uint32_t a_;                                                      \
            a_  = (uint32_t)__popc(PW[b_][0] & R[0]);                         \
            a_ += (uint32_t)__popc(PW[b_][1] & R[1]);                         \
            a_ += (uint32_t)__popc(PW[b_][2] & R[2]);                         \
            a_ += (uint32_t)__popc(PW[b_][3] & R[3]);                         \
            a_ += (uint32_t)__popc(PW[b_][4] & R[4]);                         \
            a_ += (uint32_t)__popc(PW[b_][5] & R[5]);                         \
            a_ += (uint32_t)__popc(PW[b_][6] & R[6]);                         \
            a_ += (uint32_t)__popc(PW[b_][7] & R[7]);                         \
            acc_ += a_ << b_;                                                 \
        }                                                                     \
        OUTV = acc_;                                                          \
    } while (0)

    for (int s = 0; s < S_STEPS; ++s) {
        uint32_t RA[8], RB[8];
#pragma unroll
        for (int q = 0; q < 8; ++q) { RA[q] = rmask[cur][0][q]; RB[q] = rmask[cur][1][q]; }

        // ---- sample A: idx + issue load ----
        uint32_t idxA;
        IDX_OF(RA, idxA);
        u32x2 dA, dB;
        const uint32_t oA = ((uint32_t)j << 15) + ((idxA >> 6) << 3);
        asm volatile("global_load_dwordx2 %0, %1, %2" : "=v"(dA) : "v"(oA), "s"(lpbase));

        // ---- sample B: idx (hides lpA latency) + issue load ----
        uint32_t idxB;
        IDX_OF(RB, idxB);
        const uint32_t oB = ((uint32_t)j << 15) + ((idxB >> 6) << 3);
        asm volatile("global_load_dwordx2 %0, %1, %2" : "=v"(dB) : "v"(oB), "s"(lpbase));

        // next input words (LDS; invisible to vmcnt)
        const int sn = (s + 1 < S_STEPS) ? s + 1 : s;
        const uint32_t xwnA = sxwA[sn], xwnB = sxwB[sn];
        const int inj = (s + 1 < S_STEPS) && (slot >= 0);

        asm volatile("s_waitcnt vmcnt(1)");
        asm volatile("" : "+v"(dA));
        vA = (int)(((((uint64_t)dA[1] << 32) | dA[0]) >> (idxA & 63)) & 1);
        int wbA = inj ? (int)((xwnA >> slot) & 1) : vA;

        asm volatile("s_waitcnt vmcnt(0)");
        asm volatile("" : "+v"(dB));
        vB = (int)(((((uint64_t)dB[1] << 32) | dB[0]) >> (idxB & 63)) & 1);
        int wbB = inj ? (int)((xwnB >> slot) & 1) : vB;

        const uint64_t balA = __ballot(wbA != 0);
        const uint64_t balB = __ballot(wbB != 0);
        if (l == 0) {
            rmask[cur ^ 1][0][2 * w] = (uint32_t)balA;  rmask[cur ^ 1][0][2 * w + 1] = (uint32_t)(balA >> 32);
            rmask[cur ^ 1][1][2 * w] = (uint32_t)balB;  rmask[cur ^ 1][1][2 * w + 1] = (uint32_t)(balB >> 32);
        }
        __syncthreads();
        cur ^= 1;
    }
#undef IDX_OF

    // keep readout loads out of the counted loop
    const float* rWo;
    const float* rbo;
    asm volatile("" : "=s"(rWo) : "0"(rW));
    asm volatile("" : "=s"(rbo) : "0"(rb));

    // readout for both samples
    if (j < 2 * OUT_N) lout[j / OUT_N][j % OUT_N] = 0.f;
    __syncthreads();
#pragma unroll
    for (int o = 0; o < OUT_N; ++o) {
        float cA = vA ? rWo[o * R_NODES + j] : 0.f;
        float cB = vB ? rWo[o * R_NODES + j] : 0.f;
        for (int off = 32; off > 0; off >>= 1) {
            cA += __shfl_down(cA, off, 64);
            cB += __shfl_down(cB, off, 64);
        }
        if (l == 0) { atomicAdd(&lout[0][o], cA); atomicAdd(&lout[1][o], cB); }
    }
    __syncthreads();
    if (j < OUT_N) {
        out[(size_t)(2 * m2 + 0) * OUT_N + j] = lout[0][j] + rbo[j];
        out[(size_t)(2 * m2 + 1) * OUT_N + j] = lout[1][j] + rbo[j];
    }
}

extern "C" void kernel_launch(void* const* d_in, const int* in_sizes, int n_in,
                              void* d_out, int out_size, void* d_ws, size_t ws_size,
                              hipStream_t stream) {
    const uint8_t* x        = (const uint8_t*)d_in[0];   // bool [M,S,D,B]
    const int* input_nodes  = (const int*)d_in[1];       // int32 [32]
    const int* lut          = (const int*)d_in[2];       // int32 [256, 2^18]
    const uint8_t* wres     = (const uint8_t*)d_in[3];   // bool [256,256]
    const int* primes       = (const int*)d_in[4];       // int32 [256]
    const uint8_t* init_res = (const uint8_t*)d_in[5];   // bool [256]
    const float* rW         = (const float*)d_in[6];     // f32 [10,256]
    const float* rb         = (const float*)d_in[7];     // f32 [10]
    float* out              = (float*)d_out;             // f32 [512,10]

    uint8_t* ws = (uint8_t*)d_ws;
    int*      flag = (int*)ws;                                        // 4 B
    uint32_t* xp   = (uint32_t*)(ws + 4096);                          // 1 MB
    uint64_t* lp   = (uint64_t*)(ws + 4096 + 1048576);                // 8 MB

    detect_layout<<<1, 256, 0, stream>>>(x, flag);
    pack_x<<<(M_SAMP * S_STEPS * 32) / 256, 256, 0, stream>>>(x, flag, xp);
    pack_lut<<<4096, 256, 0, stream>>>(lut, (uint32_t*)lp);
    reservoir_pop2<<<M_SAMP / 2, 256, 0, stream>>>(xp, lp, input_nodes, wres,
                                                   primes, init_res, flag,
                                                   rW, rb, out);
}

// Round 13
// 902.283 us; speedup vs baseline: 1.2324x; 1.2324x over previous
//
#include <hip/hip_runtime.h>
#include <stdint.h>

#define R_NODES 256
#define M_SAMP  512
#define S_STEPS 512
#define OUT_N   10

typedef unsigned int u32x2 __attribute__((ext_vector_type(2)));
typedef _Float16     half8 __attribute__((ext_vector_type(8)));
typedef float        f32x4 __attribute__((ext_vector_type(4)));

// ---------------- layout detection for bool inputs ----------------
// If bools were uploaded as int32, byte (4f+1) of every element is 0.
// If uploaded as uint8, ~half those bytes are 1.  flag=1 => uint8 layout.
__global__ void detect_layout(const uint8_t* __restrict__ x, int* __restrict__ flag) {
    __shared__ int any;
    if (threadIdx.x == 0) any = 0;
    __syncthreads();
    int acc = 0;
    for (int i = 0; i < 64; ++i)
        acc |= x[(size_t)(threadIdx.x * 64 + i) * 4 + 1];
    if (acc) atomicOr(&any, 1);
    __syncthreads();
    if (threadIdx.x == 0) *flag = any ? 1 : 0;
}

// ---------------- pack x bits: one uint32 per (m,s) ----------------
__global__ void pack_x(const uint8_t* __restrict__ x, const int* __restrict__ flag,
                       uint32_t* __restrict__ xp) {
    const int stride = (*flag) ? 1 : 4;
    const int f = blockIdx.x * blockDim.x + threadIdx.x;      // element idx, M*S*32 total
    const int val = x[(size_t)f * stride];
    const uint64_t mask = __ballot(val != 0);
    const int lane = threadIdx.x & 63;
    if ((lane & 31) == 0) {
        uint32_t w = (lane & 32) ? (uint32_t)(mask >> 32) : (uint32_t)mask;
        xp[f >> 5] = w;
    }
}

// ---------------- bit-pack the LUT: 256MB int32 -> 8MB bits ----------------
__device__ __forceinline__ uint32_t spread8(uint32_t x) {
    // bit i of low byte -> bit 4*i
    x = (x | (x << 12)) & 0x000F000Fu;
    x = (x | (x << 6))  & 0x03030303u;
    x = (x | (x << 3))  & 0x11111111u;
    return x;
}
__global__ void pack_lut(const int* __restrict__ lut, uint32_t* __restrict__ lp32) {
    const int lane = threadIdx.x & 63;
    const int gw = blockIdx.x * (blockDim.x >> 6) + (threadIdx.x >> 6); // 16384 waves
    const int4* src = (const int4*)lut;
    for (int it = 0; it < 16; ++it) {
        const int chunk = gw * 16 + it;                // 262144 wave-chunks total
        const int4 q = src[(size_t)chunk * 64 + lane]; // coalesced 16B/lane
        const uint64_t b0 = __ballot((q.x & 1) != 0);
        const uint64_t b1 = __ballot((q.y & 1) != 0);
        const uint64_t b2 = __ballot((q.z & 1) != 0);
        const uint64_t b3 = __ballot((q.w & 1) != 0);
        if (lane < 8) {
            const uint32_t B0 = (uint32_t)(b0 >> (8 * lane)) & 0xFF;
            const uint32_t B1 = (uint32_t)(b1 >> (8 * lane)) & 0xFF;
            const uint32_t B2 = (uint32_t)(b2 >> (8 * lane)) & 0xFF;
            const uint32_t B3 = (uint32_t)(b3 >> (8 * lane)) & 0xFF;
            const uint32_t w = spread8(B0) | (spread8(B1) << 1)
                             | (spread8(B2) << 2) | (spread8(B3) << 3);
            lp32[(size_t)chunk * 8 + lane] = w;
        }
    }
}

// ------------- main scan: MFMA matvec, ONE sample per block ---------------
// R11/R12 lesson: popcount matvec = ~440 VALU instrs/thread/step dominates
// (VALUBusy 55-65%) and the 512-sample grid caps waves/SIMD.  Offload the
// matvec to the idle MFMA pipe; R9 already VERIFIED the fragment layouts
// (passed correctness; it failed on grid size / conflicts, both fixed here).
//   512 blocks x 256 thr (4 waves, 2 blocks/CU de-phased).  Wave w owns
//   rows 64w..64w+63 as 4 m-tiles; A-frags (128 VGPR) hold W'=primes*W,
//   f16-exact (primes<2048, sums<2^24), with k-columns PERMUTED to ballot
//   order n(k') so the per-step ballot needs no unscrambling:
//     n(k') = 64(k'>>6) + 16((k'&15)>>2) + 4((k'>>4)&3) + (k'&3)
//   Per step/wave: 8 mask words from LDS -> byte (4kt+g) -> LDS byte->f16x8
//   table (same addr across each 16-lane group: broadcast, conflict-free)
//   -> B-frag REPLICATED over all 16 cols -> 32 mfma_16x16x32_f16 -> each
//   lane holds idx of node 64w+16(c>>2)+4g+(c&3) (replication = free
//   redistribution) -> 1 lp bit-load/lane (asm, counted vmcnt) -> ballot
//   -> ONE barrier.  ~90 VALU + 32 MFMA per wave-step vs R11's ~440 VALU.
__global__ __launch_bounds__(256, 2) void reservoir_mv1(
    const uint32_t* __restrict__ xp, const uint64_t* __restrict__ lp,
    const int* __restrict__ input_nodes, const uint8_t* __restrict__ wres,
    const int* __restrict__ primes, const uint8_t* __restrict__ init_res,
    const int* __restrict__ flag, const float* __restrict__ rW,
    const float* __restrict__ rb, float* __restrict__ out)
{
    const int m = blockIdx.x;
    const int t = threadIdx.x;          // 0..255
    const int l = t & 63;
    const int w = t >> 6;               // wave 0..3
    const int g = l >> 4;               // 16-lane group 0..3
    const int c = l & 15;
    const int stride = (*flag) ? 1 : 4;

    __shared__ uint32_t sxw[S_STEPS];   // 2KB input words
    __shared__ uint32_t rmask[2][8];    // state dbuf, BALLOT(k') bit order
    __shared__ uint4    tab[256];       // byte -> 8 packed f16 (0/1.0)
    __shared__ float    lout[OUT_N];

    const uint32_t* xrow = xp + m * S_STEPS;
    for (int i = t; i < S_STEPS; i += 256) sxw[i] = xrow[i];

    // byte->f16x8 expansion table (bit j of byte -> f16 j)
    {
        uint32_t pk[4];
#pragma unroll
        for (int p = 0; p < 4; ++p) {
            const uint32_t b0 = (t >> (2 * p)) & 1u;
            const uint32_t b1 = (t >> (2 * p + 1)) & 1u;
            pk[p] = b0 * 0x3C00u + b1 * 0x3C000000u;
        }
        tab[t] = make_uint4(pk[0], pk[1], pk[2], pk[3]);
    }

    // this lane's node (C-layout assignment): n = 64w + 16T + 4g + r,
    // T = c>>2, r = c&3  -- matches ballot order k' = 64w + l.
    const int T = c >> 2, r = c & 3;
    const int n = 64 * w + 16 * T + 4 * g + r;

    int slot = -1;
    for (int i = 0; i < 32; ++i)
        if (input_nodes[i] == n) slot = i;

    // ---- A fragments: af[T][kt] elem j = W'[row][ n(k') ],
    //      row = 64w + 16T + c,  k' = 32kt + 8g + j ----
    half8 af[4][8];
#pragma unroll
    for (int Ti = 0; Ti < 4; ++Ti) {
        const int row = 64 * w + 16 * Ti + c;
#pragma unroll
        for (int kt = 0; kt < 8; ++kt) {
            half8 a;
#pragma unroll
            for (int j = 0; j < 8; ++j) {
                const int kp = 32 * kt + 8 * g + j;      // k' index
                const int kn = 64 * (kp >> 6) + 16 * ((kp & 15) >> 2)
                             + 4 * ((kp >> 4) & 3) + (kp & 3);
                const int on = wres[(size_t)(row * 256 + kn) * stride] ? 1 : 0;
                a[j] = (_Float16)(on ? (float)primes[kn] : 0.f);
            }
            af[Ti][kt] = a;
        }
    }

    __syncthreads();                    // sxw + tab ready
    // init state bit for node n (x_0 injection folded), publish ballot
    {
        int bv = init_res[(size_t)n * stride] ? 1 : 0;
        if (slot >= 0) bv = (sxw[0] >> slot) & 1;
        const uint64_t bal = __ballot(bv != 0);
        if (l == 0) {
            rmask[0][2 * w]     = (uint32_t)bal;
            rmask[0][2 * w + 1] = (uint32_t)(bal >> 32);
        }
    }
    __syncthreads();

    const uint64_t lpbase = (uint64_t)(uintptr_t)lp;
    const uint32_t nb = (uint32_t)n << 15;    // lp byte base of node n
    const half8* tabh = (const half8*)tab;
    int cur = 0, v = 0;

    for (int s = 0; s < S_STEPS; ++s) {
        // ---- B-frags from mask + 32 MFMA (4 acc chains interleave) ----
        f32x4 a0 = {0,0,0,0}, a1 = {0,0,0,0}, a2 = {0,0,0,0}, a3 = {0,0,0,0};
#pragma unroll
        for (int kt = 0; kt < 8; ++kt) {
            const uint32_t byte = (rmask[cur][kt] >> (8 * g)) & 0xFFu;
            const half8 bf = tabh[byte];           // broadcast within group
            a0 = __builtin_amdgcn_mfma_f32_16x16x32_f16(af[0][kt], bf, a0, 0, 0, 0);
            a1 = __builtin_amdgcn_mfma_f32_16x16x32_f16(af[1][kt], bf, a1, 0, 0, 0);
            a2 = __builtin_amdgcn_mfma_f32_16x16x32_f16(af[2][kt], bf, a2, 0, 0, 0);
            a3 = __builtin_amdgcn_mfma_f32_16x16x32_f16(af[3][kt], bf, a3, 0, 0, 0);
        }
        // ---- pick this lane's idx: tile T, reg r (static extracts only) --
        const f32x4 at = (c < 8) ? ((c < 4) ? a0 : a1) : ((c < 12) ? a2 : a3);
        const float fv = (r == 0) ? at[0] : (r == 1) ? at[1] : (r == 2) ? at[2] : at[3];
        const uint32_t idx = (uint32_t)fv;         // exact: < 2^18

        // ---- lp bit lookup (asm, counted vmcnt) ----
        u32x2 d;
        const uint32_t o = nb + ((idx >> 6) << 3);
        asm volatile("global_load_dwordx2 %0, %1, %2" : "=v"(d) : "v"(o), "s"(lpbase));
        const int sn = (s + 1 < S_STEPS) ? s + 1 : s;
        const uint32_t xwn = sxw[sn];
        const int inj = (s + 1 < S_STEPS) && (slot >= 0);
        asm volatile("s_waitcnt vmcnt(0)");
        asm volatile("" : "+v"(d));
        v = (int)(((((uint64_t)d[1] << 32) | d[0]) >> (idx & 63)) & 1);
        const int wb = inj ? (int)((xwn >> slot) & 1) : v;

        const uint64_t bal = __ballot(wb != 0);
        if (l == 0) {
            rmask[cur ^ 1][2 * w]     = (uint32_t)bal;
            rmask[cur ^ 1][2 * w + 1] = (uint32_t)(bal >> 32);
        }
        __syncthreads();
        cur ^= 1;
    }

    // keep readout loads out of the counted loop
    const float* rWo;
    const float* rbo;
    asm volatile("" : "=s"(rWo) : "0"(rW));
    asm volatile("" : "=s"(rbo) : "0"(rb));

    // readout: out[m][o] = b[o] + sum_n v_n * W[o][n]  (n scattered per lane)
    if (t < OUT_N) lout[t] = 0.f;
    __syncthreads();
#pragma unroll
    for (int o = 0; o < OUT_N; ++o) {
        float cv = v ? rWo[o * R_NODES + n] : 0.f;
        for (int off = 32; off > 0; off >>= 1)
            cv += __shfl_down(cv, off, 64);
        if (l == 0) atomicAdd(&lout[o], cv);
    }
    __syncthreads();
    if (t < OUT_N) out[m * OUT_N + t] = lout[t] + rbo[t];
}

extern "C" void kernel_launch(void* const* d_in, const int* in_sizes, int n_in,
                              void* d_out, int out_size, void* d_ws, size_t ws_size,
                              hipStream_t stream) {
    const uint8_t* x        = (const uint8_t*)d_in[0];   // bool [M,S,D,B]
    const int* input_nodes  = (const int*)d_in[1];       // int32 [32]
    const int* lut          = (const int*)d_in[2];       // int32 [256, 2^18]
    const uint8_t* wres     = (const uint8_t*)d_in[3];   // bool [256,256]
    const int* primes       = (const int*)d_in[4];       // int32 [256]
    const uint8_t* init_res = (const uint8_t*)d_in[5];   // bool [256]
    const float* rW         = (const float*)d_in[6];     // f32 [10,256]
    const float* rb         = (const float*)d_in[7];     // f32 [10]
    float* out              = (float*)d_out;             // f32 [512,10]

    uint8_t* ws = (uint8_t*)d_ws;
    int*      flag = (int*)ws;                                        // 4 B
    uint32_t* xp   = (uint32_t*)(ws + 4096);                          // 1 MB
    uint64_t* lp   = (uint64_t*)(ws + 4096 + 1048576);                // 8 MB

    detect_layout<<<1, 256, 0, stream>>>(x, flag);
    pack_x<<<(M_SAMP * S_STEPS * 32) / 256, 256, 0, stream>>>(x, flag, xp);
    pack_lut<<<4096, 256, 0, stream>>>(lut, (uint32_t*)lp);
    reservoir_mv1<<<M_SAMP, 256, 0, stream>>>(xp, lp, input_nodes, wres,
                                              primes, init_res, flag,
                                              rW, rb, out);
}